// Round 19
// baseline (167.216 us; speedup 1.0000x reference)
//
#include <hip/hip_runtime.h>

#define NB 8
#define NS 1024
#define ND 1024
#define NH 16
#define NHD 64

typedef __attribute__((ext_vector_type(8))) short bf16x8;
typedef __attribute__((ext_vector_type(4))) float f32x4;
typedef __attribute__((ext_vector_type(4))) unsigned int u32x4;

#define GLOAD_LDS16(g, l) __builtin_amdgcn_global_load_lds(                    \
    (const __attribute__((address_space(1))) void*)(g),                        \
    (__attribute__((address_space(3))) void*)(l), 16, 0, 0)

static __device__ __forceinline__ unsigned short f2bf(float f) {
    unsigned int u = __builtin_bit_cast(unsigned int, f);
    unsigned int r = u + 0x7fffu + ((u >> 16) & 1u);
    return (unsigned short)(r >> 16);
}

static __device__ __forceinline__ unsigned int cvtpk(float lo, float hi) {
    unsigned int r;
    asm("v_cvt_pk_bf16_f32 %0, %1, %2" : "=v"(r) : "v"(lo), "v"(hi));
    return r;
}

// load float from LDS table by BYTE offset (rel codes are pre-shifted <<2)
static __device__ __forceinline__ float ldre(const float* t, unsigned int byteoff) {
    return *reinterpret_cast<const float*>(reinterpret_cast<const char*>(t) + byteoff);
}

// ---------------- fp32 -> bf16 convert ----------------
__global__ void cvt_f32_bf16(const float* __restrict__ in, unsigned short* __restrict__ out, int n) {
    int i = (blockIdx.x * blockDim.x + threadIdx.x) * 4;
    if (i >= n) return;
    float4 v = *reinterpret_cast<const float4*>(in + i);
    ushort4 o;
    o.x = f2bf(v.x); o.y = f2bf(v.y); o.z = f2bf(v.z); o.w = f2bf(v.w);
    *reinterpret_cast<ushort4*>(out + i) = o;
}

// 3 weight matrices in one launch (grid.y selects source)
__global__ void cvt_w3(const float* __restrict__ Wq, const float* __restrict__ Wk,
                       const float* __restrict__ Wv, unsigned short* __restrict__ out) {
    const float* src = (blockIdx.y == 0) ? Wq : (blockIdx.y == 1) ? Wk : Wv;
    int i = (blockIdx.x * blockDim.x + threadIdx.x) * 4;
    float4 v = *reinterpret_cast<const float4*>(src + i);
    ushort4 o;
    o.x = f2bf(v.x); o.y = f2bf(v.y); o.z = f2bf(v.z); o.w = f2bf(v.w);
    *reinterpret_cast<ushort4*>(out + (size_t)blockIdx.y * (ND * ND) + i) = o;
}

// rel int32 -> packed int8, PRE-SHIFTED <<2 (byte value = LDS float byte-offset).
__global__ void pack_rel8(const int* __restrict__ rel, unsigned int* __restrict__ out) {
    int i = blockIdx.x * blockDim.x + threadIdx.x;
    int4 v = reinterpret_cast<const int4*>(rel)[i];
    out[i] = ((unsigned)v.x << 2) | ((unsigned)v.y << 10) |
             ((unsigned)v.z << 18) | ((unsigned)v.w << 26);
}

// ---------------- QKV projection GEMM (r17: LDS-bounce epilogue) ----------------
__global__ __launch_bounds__(256) void qkv_gemm(
    const unsigned short* __restrict__ A,
    const unsigned short* __restrict__ Wq, const unsigned short* __restrict__ Wk,
    const unsigned short* __restrict__ Wv,
    const float* __restrict__ bq, const float* __restrict__ bk, const float* __restrict__ bv,
    const float* __restrict__ mask,
    unsigned short* __restrict__ Qo, unsigned short* __restrict__ Ko, unsigned short* __restrict__ Vo)
{
    const int z = blockIdx.z;
    const unsigned short* W = (z == 0) ? Wq : (z == 1) ? Wk : Wv;
    const float* bias = (z == 0) ? bq : (z == 1) ? bk : bv;
    const int m0 = blockIdx.x * 128;
    const int n0 = blockIdx.y * 128;
    const float LOG2E = 1.4426950408889634f;
    const float QSCL = 0.125f * 1.4426950408889634f;

    __shared__ unsigned short S[2][128][64];   // As=S[0], Bs=S[1]; 32 KB total

    const int tid = threadIdx.x;
    const int lane = tid & 63;
    const int wave = tid >> 6;
    const int wm = wave >> 1, wn = wave & 1;
    const int g = lane >> 4, l15 = lane & 15;

    f32x4 acc[4][4] = {};

    const int crow = lane >> 3;                    // row within chunk 0..7
    const int gcol = ((lane & 7) ^ crow) * 8;      // pre-swizzled source col (elems)
    const int kofs = g * 8;

    for (int kb = 0; kb < ND; kb += 64) {
#pragma unroll
        for (int cc = 0; cc < 4; ++cc) {
            int ch = wave * 4 + cc;                // 16 chunks each
            GLOAD_LDS16(&A[(size_t)(m0 + ch * 8 + crow) * ND + kb + gcol], &S[0][ch * 8][0]);
            GLOAD_LDS16(&W[(size_t)(n0 + ch * 8 + crow) * ND + kb + gcol], &S[1][ch * 8][0]);
        }
        __syncthreads();
#pragma unroll
        for (int kk = 0; kk < 2; ++kk) {
            const int colx = (kk * 32 + kofs) ^ ((lane & 7) * 8);
            bf16x8 af[4], bfr[4];
#pragma unroll
            for (int i = 0; i < 4; ++i) {
                af[i]  = *reinterpret_cast<const bf16x8*>(&S[0][wm * 64 + i * 16 + l15][colx]);
                bfr[i] = *reinterpret_cast<const bf16x8*>(&S[1][wn * 64 + i * 16 + l15][colx]);
            }
#pragma unroll
            for (int mi = 0; mi < 4; ++mi)
#pragma unroll
                for (int ni = 0; ni < 4; ++ni)
                    acc[mi][ni] = __builtin_amdgcn_mfma_f32_16x16x32_bf16(af[mi], bfr[ni], acc[mi][ni], 0, 0, 0);
        }
        __syncthreads();
    }

    // -------- LDS-bounce epilogue: per-wave 8 KB slice of S --------
    __syncthreads();   // all waves done reading S
    char* L = reinterpret_cast<char*>(&S[0][0][0]) + wave * 8192;
    const int rrow = lane >> 3, cb = lane & 7;

    if (z == 2) {
#pragma unroll
        for (int ni = 0; ni < 4; ++ni) {
            int n = n0 + wn * 64 + ni * 16 + l15;
            int nl = ni * 16 + l15;
            float bv_ = bias[n];
#pragma unroll
            for (int mi = 0; mi < 4; ++mi) {
                int m = m0 + wm * 64 + mi * 16 + g * 4;
                int b = m >> 10, s = m & 1023;
                float4 mv = *reinterpret_cast<const float4*>(&mask[(size_t)b * NS + s]);
                unsigned int lo = cvtpk((acc[mi][ni][0] + bv_) * exp2f(mv.x * LOG2E),
                                        (acc[mi][ni][1] + bv_) * exp2f(mv.y * LOG2E));
                unsigned int hi = cvtpk((acc[mi][ni][2] + bv_) * exp2f(mv.z * LOG2E),
                                        (acc[mi][ni][3] + bv_) * exp2f(mv.w * LOG2E));
                int ml = mi * 16 + g * 4;
                int off = nl * 128 + (((ml >> 3) ^ (nl & 7)) * 16) + (ml & 7) * 2;
                *reinterpret_cast<uint2*>(L + off) = make_uint2(lo, hi);
            }
        }
#pragma unroll
        for (int p = 0; p < 8; ++p) {
            int nl = p * 8 + rrow;
            u32x4 v = *reinterpret_cast<const u32x4*>(L + nl * 128 + ((cb ^ (nl & 7)) * 16));
            int n = n0 + wn * 64 + nl;
            int h = n >> 6, hd = n & 63;
            int m = m0 + wm * 64 + cb * 8;
            int b = m >> 10, s = m & 1023;
            *reinterpret_cast<u32x4*>(&Vo[(((size_t)b * NH + h) * NHD + hd) * NS + s]) = v;
        }
    } else {
        unsigned short* O = (z == 0) ? Qo : Ko;
#pragma unroll
        for (int ni = 0; ni < 4; ++ni) {
            int n = n0 + wn * 64 + ni * 16 + l15;
            int nl = ni * 16 + l15;
            float bv_ = bias[n];
            int c16 = nl >> 3, bin = (nl & 7) * 2;
#pragma unroll
            for (int mi = 0; mi < 4; ++mi) {
#pragma unroll
                for (int r = 0; r < 4; ++r) {
                    int ml = mi * 16 + g * 4 + r;
                    float v = acc[mi][ni][r] + bv_;
                    if (z == 0) v *= QSCL;
                    int off = ml * 128 + ((c16 ^ (ml & 7)) * 16) + bin;
                    *reinterpret_cast<unsigned short*>(L + off) = f2bf(v);
                }
            }
        }
#pragma unroll
        for (int p = 0; p < 8; ++p) {
            int ml = p * 8 + rrow;
            u32x4 v = *reinterpret_cast<const u32x4*>(L + ml * 128 + ((cb ^ (ml & 7)) * 16));
            int m = m0 + wm * 64 + ml;
            int b = m >> 10, s = m & 1023;
            int n = n0 + wn * 64 + cb * 8;
            int h = n >> 6, hd = n & 63;
            *reinterpret_cast<u32x4*>(&O[(((size_t)b * NH + h) * NS + s) * NHD + hd]) = v;
        }
    }
}

// ---------------- flash attention: 4 waves x 32 q-rows (q-register-tiling x2) ----
// flat grid 1024, block 256 (4 waves). Wave owns q-rows [wave*32, +32) as TWO
// 16-row groups; K-frag and V-frag ds_reads are loaded ONCE and reused by both
// groups' MFMAs -> LDS b128 traffic per q-row HALVES (flash was ~84%
// LDS-throughput-bound: 18 b128 + 16 b32 per wave-tile at 32 waves/CU).
// Register-set names use letter-led suffixes (rAa0 etc.) because `r##S##0a.x`
// pastes into an invalid pp-number token (round-18 compile failure).
__global__ __launch_bounds__(256) void flash_attn(
    const unsigned short* __restrict__ Q, const unsigned short* __restrict__ Kb,
    const unsigned short* __restrict__ Vt,
    const unsigned char* __restrict__ rel8, const float* __restrict__ rel_emb,
    const float* __restrict__ mask, float* __restrict__ out)
{
    const int id = blockIdx.x;
    const int b = id & 7;                 // XCD-clustered batch
    const int h = (id >> 3) & 15;
    const int q0 = (id >> 7) * 128;
    const int tid = threadIdx.x, lane = tid & 63, wave = tid >> 6;  // wave 0..3
    const int g = lane >> 4, l15 = lane & 15;

    __shared__ unsigned short Ks[2][64][64]; // [buf][perm-kv][hd], chunk-swizzled, 16 KB
    __shared__ unsigned short Vs[2][64][64]; // [buf][hd][kv], chunk-swizzled, 16 KB
    __shared__ unsigned short s_emask[NS];   // bf16 exp2(mask*log2e), 2 KB
    __shared__ float s_re2[8];               // rel_emb[.][h] * log2(e) - 4.0
    const float LOG2E = 1.4426950408889634f;
    if (tid < 7) s_re2[tid] = rel_emb[tid * NH + h] * LOG2E - 4.0f;

    const unsigned short* Qh = Q  + (((size_t)b * NH + h) * NS) * NHD;
    const unsigned short* Kh = Kb + (((size_t)b * NH + h) * NS) * NHD;
    const unsigned short* Vh = Vt + (((size_t)b * NH + h) * NHD) * NS;
    const int qg0 = q0 + wave * 32 + l15;            // group-0 q-row
    const int qg1 = qg0 + 16;                        // group-1 q-row
    const unsigned char* __restrict__ relrow0 = rel8 + (size_t)b * NS * NS + (size_t)qg0 * NS;
    const unsigned char* __restrict__ relrow1 = relrow0 + 16 * NS;
    const float* __restrict__ maskb = mask + (size_t)b * NS;

    bf16x8 qa0[2], qa1[2];
    qa0[0] = *reinterpret_cast<const bf16x8*>(&Qh[(size_t)qg0 * NHD + g * 8]);
    qa0[1] = *reinterpret_cast<const bf16x8*>(&Qh[(size_t)qg0 * NHD + 32 + g * 8]);
    qa1[0] = *reinterpret_cast<const bf16x8*>(&Qh[(size_t)qg1 * NHD + g * 8]);
    qa1[1] = *reinterpret_cast<const bf16x8*>(&Qh[(size_t)qg1 * NHD + 32 + g * 8]);

    f32x4 ctx0[4] = {}, ctx1[4] = {};
    f32x4 l_acc0 = {}, l_acc1 = {};
    float mofs0 = 0.f, mofs1 = 0.f;      // running max minus folded base (4.0)
    bool everscaled = false;             // sticky, wave-uniform

    const int crow = lane >> 3;
    const int gcol = ((lane & 7) ^ crow) * 8;
    const int swz8 = (lane & 7) * 8;

    // K row-permutation (loop-invariant): wave stages LDS rows [wave*16, +16)
    const int rho0 = wave * 16 + crow;
    const int rho1 = rho0 + 8;
#define KVPERM(r) ((((r) >> 5) << 5) + ((((r) >> 2) & 3) << 3) + ((((r) >> 4) & 1) << 2) + ((r) & 3))
    const int kvp0 = KVPERM(rho0);
    const int kvp1 = KVPERM(rho1);
#undef KVPERM

#define STAGE(buf, kv)                                                                              \
    {                                                                                               \
        GLOAD_LDS16(&Kh[(size_t)((kv) + kvp0) * NHD + gcol], &Ks[buf][wave * 16][0]);               \
        GLOAD_LDS16(&Kh[(size_t)((kv) + kvp1) * NHD + gcol], &Ks[buf][wave * 16 + 8][0]);           \
        GLOAD_LDS16(&Vh[(size_t)(wave * 16 + crow) * NS + (kv) + gcol], &Vs[buf][wave * 16][0]);    \
        GLOAD_LDS16(&Vh[(size_t)(wave * 16 + 8 + crow) * NS + (kv) + gcol], &Vs[buf][wave * 16 + 8][0]); \
    }

#define LOADRM(S, t0)                                                                  \
    {                                                                                  \
        r##S##a0 = *reinterpret_cast<const uint2*>(&relrow0[(t0) * 64 + 8 * g]);       \
        r##S##b0 = *reinterpret_cast<const uint2*>(&relrow0[(t0) * 64 + 32 + 8 * g]);  \
        r##S##a1 = *reinterpret_cast<const uint2*>(&relrow1[(t0) * 64 + 8 * g]);       \
        r##S##b1 = *reinterpret_cast<const uint2*>(&relrow1[(t0) * 64 + 32 + 8 * g]);  \
    }

    uint2 rAa0, rAb0, rAa1, rAb1, rBa0, rBb0, rBa1, rBb1;

    STAGE(0, 0)
    LOADRM(A, 0)
#pragma unroll
    for (int i = 0; i < 4; ++i)
        s_emask[tid + i * 256] = f2bf(exp2f(maskb[tid + i * 256] * LOG2E));
    __syncthreads();

#define BODY(cur, S, SN, tc, tn)                                               \
  {                                                                            \
    if ((tn) < 16) {                                                           \
      STAGE(cur ^ 1, (tn) * 64)                                                \
      LOADRM(SN, tn)                                                           \
    }                                                                          \
    f32x4 sc0[4] = {}, sc1[4] = {};                                            \
    __builtin_amdgcn_s_setprio(1);                                             \
    _Pragma("unroll")                                                          \
    for (int kk = 0; kk < 2; ++kk) {                                           \
      const int colx = (kk * 32 + g * 8) ^ swz8;                               \
      bf16x8 kfrag[4];                                                         \
      _Pragma("unroll")                                                        \
      for (int tt = 0; tt < 4; ++tt)                                           \
        kfrag[tt] = *reinterpret_cast<const bf16x8*>(&Ks[cur][tt * 16 + l15][colx]); \
      _Pragma("unroll")                                                        \
      for (int tt = 0; tt < 4; ++tt)                                           \
        sc0[tt] = __builtin_amdgcn_mfma_f32_16x16x32_bf16(kfrag[tt], qa0[kk], sc0[tt], 0, 0, 0); \
      _Pragma("unroll")                                                        \
      for (int tt = 0; tt < 4; ++tt)                                           \
        sc1[tt] = __builtin_amdgcn_mfma_f32_16x16x32_bf16(kfrag[tt], qa1[kk], sc1[tt], 0, 0, 0); \
    }                                                                          \
    __builtin_amdgcn_s_setprio(0);                                             \
    const unsigned int rw0[4] = {r##S##a0.x, r##S##a0.y, r##S##b0.x, r##S##b0.y}; \
    const unsigned int rw1[4] = {r##S##a1.x, r##S##a1.y, r##S##b1.x, r##S##b1.y}; \
    float pmax0 = -1e30f, pmax1 = -1e30f;                                      \
    _Pragma("unroll")                                                          \
    for (int tt = 0; tt < 4; ++tt) {                                           \
      float a0 = sc0[tt][0] + ldre(s_re2, rw0[tt] & 0xFF);                     \
      float a1 = sc0[tt][1] + ldre(s_re2, (rw0[tt] >> 8) & 0xFF);              \
      float a2 = sc0[tt][2] + ldre(s_re2, (rw0[tt] >> 16) & 0xFF);             \
      float a3 = sc0[tt][3] + ldre(s_re2, rw0[tt] >> 24);                      \
      sc0[tt][0] = a0; sc0[tt][1] = a1; sc0[tt][2] = a2; sc0[tt][3] = a3;      \
      pmax0 = fmaxf(pmax0, fmaxf(fmaxf(a0, a1), fmaxf(a2, a3)));               \
      float b0 = sc1[tt][0] + ldre(s_re2, rw1[tt] & 0xFF);                     \
      float b1 = sc1[tt][1] + ldre(s_re2, (rw1[tt] >> 8) & 0xFF);              \
      float b2 = sc1[tt][2] + ldre(s_re2, (rw1[tt] >> 16) & 0xFF);             \
      float b3 = sc1[tt][3] + ldre(s_re2, rw1[tt] >> 24);                      \
      sc1[tt][0] = b0; sc1[tt][1] = b1; sc1[tt][2] = b2; sc1[tt][3] = b3;      \
      pmax1 = fmaxf(pmax1, fmaxf(fmaxf(b0, b1), fmaxf(b2, b3)));               \
    }                                                                          \
    if (!__all((pmax0 <= mofs0 + 8.0f) && (pmax1 <= mofs1 + 8.0f))) {          \
      float pm0 = fmaxf(pmax0, __shfl_xor(pmax0, 16));                         \
      pm0 = fmaxf(pm0, __shfl_xor(pm0, 32));                                   \
      float pm1 = fmaxf(pmax1, __shfl_xor(pmax1, 16));                         \
      pm1 = fmaxf(pm1, __shfl_xor(pm1, 32));                                   \
      float mn0 = fmaxf(mofs0, pm0), mn1 = fmaxf(mofs1, pm1);                  \
      float al0 = exp2f(mofs0 - mn0), al1 = exp2f(mofs1 - mn1);                \
      mofs0 = mn0; mofs1 = mn1;                                                \
      everscaled = true;                                                       \
      float ar0[4], ar1[4];                                                    \
      _Pragma("unroll")                                                        \
      for (int r = 0; r < 4; ++r) { ar0[r] = __shfl(al0, 4 * g + r); ar1[r] = __shfl(al1, 4 * g + r); } \
      _Pragma("unroll")                                                        \
      for (int r = 0; r < 4; ++r) { l_acc0[r] *= ar0[r]; l_acc1[r] *= ar1[r]; }\
      _Pragma("unroll")                                                        \
      for (int ht = 0; ht < 4; ++ht)                                           \
        _Pragma("unroll")                                                      \
        for (int r = 0; r < 4; ++r) { ctx0[ht][r] *= ar0[r]; ctx1[ht][r] *= ar1[r]; } \
    }                                                                          \
    unsigned int pw0[8], pw1[8];                                               \
    if (!everscaled) {                                                         \
      _Pragma("unroll")                                                        \
      for (int tt = 0; tt < 4; ++tt) {                                         \
        pw0[2 * tt]     = cvtpk(exp2f(sc0[tt][0]), exp2f(sc0[tt][1]));         \
        pw0[2 * tt + 1] = cvtpk(exp2f(sc0[tt][2]), exp2f(sc0[tt][3]));         \
        pw1[2 * tt]     = cvtpk(exp2f(sc1[tt][0]), exp2f(sc1[tt][1]));         \
        pw1[2 * tt + 1] = cvtpk(exp2f(sc1[tt][2]), exp2f(sc1[tt][3]));         \
      }                                                                        \
    } else {                                                                   \
      _Pragma("unroll")                                                        \
      for (int tt = 0; tt < 4; ++tt) {                                         \
        pw0[2 * tt]     = cvtpk(exp2f(sc0[tt][0] - mofs0), exp2f(sc0[tt][1] - mofs0)); \
        pw0[2 * tt + 1] = cvtpk(exp2f(sc0[tt][2] - mofs0), exp2f(sc0[tt][3] - mofs0)); \
        pw1[2 * tt]     = cvtpk(exp2f(sc1[tt][0] - mofs1), exp2f(sc1[tt][1] - mofs1)); \
        pw1[2 * tt + 1] = cvtpk(exp2f(sc1[tt][2] - mofs1), exp2f(sc1[tt][3] - mofs1)); \
      }                                                                        \
    }                                                                          \
    __builtin_amdgcn_s_setprio(1);                                             \
    _Pragma("unroll")                                                          \
    for (int kk = 0; kk < 2; ++kk) {                                           \
      const int colx = (kk * 32 + g * 8) ^ swz8;                               \
      bf16x8 bfrag[4];                                                         \
      _Pragma("unroll")                                                        \
      for (int ht = 0; ht < 4; ++ht)                                           \
        bfrag[ht] = *reinterpret_cast<const bf16x8*>(&Vs[cur][ht * 16 + l15][colx]); \
      bf16x8 mfr = *reinterpret_cast<const bf16x8*>(&s_emask[(tc) * 64 + kk * 32 + g * 8]); \
      u32x4 paw0 = {pw0[4 * kk], pw0[4 * kk + 1], pw0[4 * kk + 2], pw0[4 * kk + 3]}; \
      bf16x8 pa0 = __builtin_bit_cast(bf16x8, paw0);                           \
      l_acc0 = __builtin_amdgcn_mfma_f32_16x16x32_bf16(pa0, mfr, l_acc0, 0, 0, 0); \
      _Pragma("unroll")                                                        \
      for (int ht = 0; ht < 4; ++ht)                                           \
        ctx0[ht] = __builtin_amdgcn_mfma_f32_16x16x32_bf16(pa0, bfrag[ht], ctx0[ht], 0, 0, 0); \
      u32x4 paw1 = {pw1[4 * kk], pw1[4 * kk + 1], pw1[4 * kk + 2], pw1[4 * kk + 3]}; \
      bf16x8 pa1 = __builtin_bit_cast(bf16x8, paw1);                           \
      l_acc1 = __builtin_amdgcn_mfma_f32_16x16x32_bf16(pa1, mfr, l_acc1, 0, 0, 0); \
      _Pragma("unroll")                                                        \
      for (int ht = 0; ht < 4; ++ht)                                           \
        ctx1[ht] = __builtin_amdgcn_mfma_f32_16x16x32_bf16(pa1, bfrag[ht], ctx1[ht], 0, 0, 0); \
    }                                                                          \
    __builtin_amdgcn_s_setprio(0);                                             \
    __syncthreads();                                                           \
  }

    for (int t = 0; t < 16; t += 2) {
        BODY(0, A, B, t, t + 1)
        BODY(1, B, A, t + 1, t + 2)
    }
#undef BODY
#undef LOADRM
#undef STAGE

    // epilogue: l_acc already in ctx layout (row = q_local = 4g+r per group)
    float li0[4], li1[4];
#pragma unroll
    for (int r = 0; r < 4; ++r) { li0[r] = 1.0f / l_acc0[r]; li1[r] = 1.0f / l_acc1[r]; }
#pragma unroll
    for (int ht = 0; ht < 4; ++ht) {
        int hd = ht * 16 + l15;
#pragma unroll
        for (int r = 0; r < 4; ++r) {
            int qo0 = q0 + wave * 32 + 4 * g + r;
            out[((size_t)b * NS + qo0) * ND + h * NHD + hd] = ctx0[ht][r] * li0[r];
            out[((size_t)b * NS + qo0 + 16) * ND + h * NHD + hd] = ctx1[ht][r] * li1[r];
        }
    }
}

extern "C" void kernel_launch(void* const* d_in, const int* in_sizes, int n_in,
                              void* d_out, int out_size, void* d_ws, size_t ws_size,
                              hipStream_t stream) {
    const float* hs      = (const float*)d_in[0];
    const float* mask    = (const float*)d_in[1];
    const int*   rel     = (const int*)d_in[2];
    const float* Wq      = (const float*)d_in[3];
    const float* bq      = (const float*)d_in[4];
    const float* Wk      = (const float*)d_in[5];
    const float* bk      = (const float*)d_in[6];
    const float* Wv      = (const float*)d_in[7];
    const float* bv      = (const float*)d_in[8];
    const float* rel_emb = (const float*)d_in[9];
    float* out = (float*)d_out;

    char* ws = (char*)d_ws;
    unsigned short* q_bf  = (unsigned short*)(ws);                       // 16 MB
    unsigned short* k_bf  = (unsigned short*)(ws + ((size_t)16 << 20));  // 16 MB
    unsigned short* vt_bf = (unsigned short*)(ws + ((size_t)32 << 20));  // 16 MB
    unsigned short* hs_bf = (unsigned short*)(ws + ((size_t)48 << 20));  // 16 MB (freed after gemm)
    unsigned short* w_bf  = (unsigned short*)(ws + ((size_t)64 << 20));  // 6 MB
    unsigned char*  rel8  = (unsigned char*)(ws + ((size_t)48 << 20));   // 8.4 MB, reuses hs_bf

    const int nhs = NB * NS * ND;       // 8.4M
    const int nw  = ND * ND;            // 1M
    cvt_f32_bf16<<<nhs / 4 / 256, 256, 0, stream>>>(hs, hs_bf, nhs);
    cvt_w3<<<dim3(nw / 4 / 256, 3), 256, 0, stream>>>(Wq, Wk, Wv, w_bf);

    qkv_gemm<<<dim3((NB * NS) / 128, ND / 128, 3), 256, 0, stream>>>(
        hs_bf, w_bf, w_bf + (size_t)nw, w_bf + (size_t)2 * nw,
        bq, bk, bv, mask, q_bf, k_bf, vt_bf);

    // hs_bf is dead after qkv_gemm; pack rel into its space
    pack_rel8<<<(NB * NS * NS / 4) / 256, 256, 0, stream>>>(rel, (unsigned int*)rel8);

    flash_attn<<<1024, 256, 0, stream>>>(
        q_bf, k_bf, vt_bf, rel8, rel_emb, mask, out);
}